// Round 5
// baseline (99.578 us; speedup 1.0000x reference)
//
#include <hip/hip_runtime.h>

// FixedActionDecoder: sims = (X/||x||) @ (A/||a||cols); segment-max over
// ACTION_INDEX=[0,0,0,0,1,1,1,1,1,2,3]; argmax; one-hot.
// Row-norm of X is argmax-invariant -> skipped.
//
//   prep   : normalize A in f64 -> W32 (ws+0, chunked) + W64 (ws+4096).
//   decode : f32 memory-bound pass. Per wave: 128-row tiles, double-buffered
//            HALF-ROW phases staged via global_load_lds (async DMA, 16 B),
//            linear LDS dest + source-side XOR swizzle (rule 21: same
//            involution on read) -> 0 bank conflicts, 0 staging VGPRs,
//            16 KB in flight per wave. Counted s_waitcnt vmcnt(16) (T4);
//            never drain to 0 mid-loop. W read via uniform-index loads from
//            a __restrict__ kernarg pointer inside #pragma unroll 1 (r2
//            lesson: no bulk hoisting) -> no more 176 LDS-broadcast
//            b128s/tile. Near-ties (gap < TAU) flagged via __ballot into
//            g_bits (device global -- r3 lesson: never overlaps ws).
//   repair : recompute flagged rows (~1e3 of 1e6) in f64 (r1/r2-validated
//            numerics path).

#define NP 11
#define TAU 1e-3f

__device__ unsigned long long g_bits[1 << 20];  // near-tie flags, 1 bit/row

__global__ void prep(const float* __restrict__ A, void* __restrict__ ws) {
    float* W32 = (float*)ws;                    // [(d>>2)*44 + (d&3)*11 + p]
    double* W64 = (double*)((char*)ws + 4096);  // [d*11 + p]
    int p = threadIdx.x;
    if (p < NP) {
        double ss = 0.0;
        for (int d = 0; d < 64; ++d) { double v = (double)A[d * NP + p]; ss += v * v; }
        double sc = 1.0 / fmax(sqrt(ss), 1e-8);
        for (int d = 0; d < 64; ++d) {
            double w = (double)A[d * NP + p] * sc;
            W64[d * NP + p] = w;
            W32[(d >> 2) * 44 + (d & 3) * NP + p] = (float)w;
        }
    }
}

// Issue one half-row phase (128 rows x 32 floats = 16 KB) as 16 async
// global_load_lds_dwordx4. LDS dest is linear (slot = i*64+lane, 16 B each);
// the source f-index is pre-swizzled so the swizzled READ is conflict-free.
#define ISSUE(tbase, phase, ldsbuf)                                            \
    {                                                                          \
        _Pragma("unroll") for (int i = 0; i < 16; ++i) {                       \
            int row_local = i * 8 + (lane >> 3);                               \
            int r = (tbase) + row_local;                                       \
            if (r >= B) r = B - 1; /* tail clamp: dup read, never stored */    \
            const float4* src = X4 + (size_t)r * 16 + (phase) * 8 + fsrc;      \
            __builtin_amdgcn_global_load_lds(                                  \
                (const __attribute__((address_space(1))) void*)src,            \
                (__attribute__((address_space(3))) void*)((ldsbuf) + i * 64),  \
                16, 0, 0);                                                     \
        }                                                                      \
    }

// Consume one phase: per kk-chunk, 2 swizzled lane b128 X-reads + 44 uniform
// W loads (scalar/L1 path, NOT LDS broadcast) + 88 v_fma_f32.
#define COMPUTE(phase, buf)                                                    \
    {                                                                          \
        _Pragma("unroll 1") for (int kk = 0; kk < 8; ++kk) {                   \
            const int sw = kk ^ s7;                                            \
            float4 x0 = (buf)[lane * 8 + sw];                                  \
            float4 x1 = (buf)[(lane + 64) * 8 + sw];                           \
            const float* wrow = W + ((phase) * 8 + kk) * 44;                   \
            _Pragma("unroll") for (int p = 0; p < NP; ++p) {                   \
                float w0 = wrow[p], w1 = wrow[NP + p];                         \
                float w2 = wrow[2 * NP + p], w3 = wrow[3 * NP + p];            \
                float t0 = fmaf(x0.x, w0, acc0[p]);                            \
                t0 = fmaf(x0.y, w1, t0);                                       \
                t0 = fmaf(x0.z, w2, t0);                                       \
                acc0[p] = fmaf(x0.w, w3, t0);                                  \
                float t1 = fmaf(x1.x, w0, acc1[p]);                            \
                t1 = fmaf(x1.y, w1, t1);                                       \
                t1 = fmaf(x1.z, w2, t1);                                       \
                acc1[p] = fmaf(x1.w, w3, t1);                                  \
            }                                                                  \
        }                                                                      \
    }

__device__ __forceinline__ void argmax_gap(const float* s, int& idx, float& gap) {
    // Segment max per ACTION_INDEX = [0,0,0,0, 1,1,1,1,1, 2, 3]
    float m0 = fmaxf(fmaxf(s[0], s[1]), fmaxf(s[2], s[3]));
    float m1 = fmaxf(fmaxf(fmaxf(s[4], s[5]), s[6]), fmaxf(s[7], s[8]));
    float m2 = s[9], m3 = s[10];
    idx = 0; float best = m0;
    if (m1 > best) { best = m1; idx = 1; }
    if (m2 > best) { best = m2; idx = 2; }
    if (m3 > best) { best = m3; idx = 3; }
    float second = -3.4e38f;
    if (idx != 0) second = fmaxf(second, m0);
    if (idx != 1) second = fmaxf(second, m1);
    if (idx != 2) second = fmaxf(second, m2);
    if (idx != 3) second = fmaxf(second, m3);
    gap = best - second;
}

__global__ __launch_bounds__(128) void decode(const float* __restrict__ X,
                                              float* __restrict__ out,
                                              const float* __restrict__ W,
                                              int B) {
    // 2 waves x 2 phase-buffers x 16 KB = 64 KB (2 blocks/CU).
    __shared__ float4 sbuf[2][2][1024];

    const int tid = threadIdx.x;
    const int lane = tid & 63;
    const int wv = tid >> 6;
    const int s7 = lane & 7;
    const int fsrc = s7 ^ (lane >> 3);  // source-side swizzle (involution)
    float4* buf0 = &sbuf[wv][0][0];
    float4* buf1 = &sbuf[wv][1][0];

    const float4* X4 = reinterpret_cast<const float4*>(X);
    const int gwave = blockIdx.x * 2 + wv;
    const int stride = gridDim.x * 2 * 128;
    const int base0 = gwave * 128;
    if (base0 >= B) return;

    // Prologue: fill both phase buffers of the first tile (32 outstanding).
    ISSUE(base0, 0, buf0);
    ISSUE(base0, 1, buf1);

    #pragma unroll 1
    for (int base = base0; base < B; base += stride) {
        const int next = base + stride;
        const bool pf = next < B;

        float acc0[NP], acc1[NP];
        #pragma unroll
        for (int p = 0; p < NP; ++p) { acc0[p] = 0.0f; acc1[p] = 0.0f; }

        // --- phase 0: wait for this tile's P0 (16 newest stay in flight) ---
        asm volatile("s_waitcnt vmcnt(16)" ::: "memory");
        __builtin_amdgcn_sched_barrier(0);
        COMPUTE(0, buf0);
        if (pf) ISSUE(next, 0, buf0);  // buf0 free now

        // --- phase 1 ---
        if (pf) {
            asm volatile("s_waitcnt vmcnt(16)" ::: "memory");
        } else {
            asm volatile("s_waitcnt vmcnt(0)" ::: "memory");
        }
        __builtin_amdgcn_sched_barrier(0);
        COMPUTE(1, buf1);
        if (pf) ISSUE(next, 1, buf1);

        // --- epilogue: argmax + flag + one-hot store (register-only) ---
        int idx0, idx1; float gap0, gap1;
        argmax_gap(acc0, idx0, gap0);
        argmax_gap(acc1, idx1, gap1);

        unsigned long long m0 = __ballot(gap0 < TAU);
        unsigned long long m1 = __ballot(gap1 < TAU);
        if (lane == 0) {
            g_bits[(base >> 6) + 0] = m0;
            g_bits[(base >> 6) + 1] = m1;
        }

        int r0 = base + lane, r1 = base + 64 + lane;
        if (r0 < B) {
            float4 o;
            o.x = (idx0 == 0) ? 1.0f : 0.0f;
            o.y = (idx0 == 1) ? 1.0f : 0.0f;
            o.z = (idx0 == 2) ? 1.0f : 0.0f;
            o.w = (idx0 == 3) ? 1.0f : 0.0f;
            reinterpret_cast<float4*>(out)[r0] = o;
        }
        if (r1 < B) {
            float4 o;
            o.x = (idx1 == 0) ? 1.0f : 0.0f;
            o.y = (idx1 == 1) ? 1.0f : 0.0f;
            o.z = (idx1 == 2) ? 1.0f : 0.0f;
            o.w = (idx1 == 3) ? 1.0f : 0.0f;
            reinterpret_cast<float4*>(out)[r1] = o;
        }
    }
}

__global__ __launch_bounds__(256) void repair(const float* __restrict__ X,
                                              float* __restrict__ out,
                                              const void* __restrict__ ws,
                                              int B) {
    const double* W64 = (const double*)((const char*)ws + 4096);
    const int nwords = (B + 63) >> 6;
    for (int t = blockIdx.x * blockDim.x + threadIdx.x; t < nwords;
         t += gridDim.x * blockDim.x) {
        unsigned long long m = g_bits[t];
        while (m) {
            int b = __builtin_ctzll(m);
            m &= m - 1;
            int row = t * 64 + b;
            if (row >= B) continue;

            double s[NP];
            #pragma unroll
            for (int p = 0; p < NP; ++p) s[p] = 0.0;
            #pragma unroll 1
            for (int d = 0; d < 64; ++d) {
                double x = (double)X[(size_t)row * 64 + d];
                #pragma unroll
                for (int p = 0; p < NP; ++p)
                    s[p] = fma(x, W64[d * NP + p], s[p]);
            }

            double m0 = fmax(fmax(s[0], s[1]), fmax(s[2], s[3]));
            double m1 = fmax(fmax(fmax(s[4], s[5]), s[6]), fmax(s[7], s[8]));
            double m2 = s[9], m3 = s[10];
            int idx = 0; double best = m0;
            if (m1 > best) { best = m1; idx = 1; }
            if (m2 > best) { best = m2; idx = 2; }
            if (m3 > best) { best = m3; idx = 3; }

            float4 o;
            o.x = (idx == 0) ? 1.0f : 0.0f;
            o.y = (idx == 1) ? 1.0f : 0.0f;
            o.z = (idx == 2) ? 1.0f : 0.0f;
            o.w = (idx == 3) ? 1.0f : 0.0f;
            reinterpret_cast<float4*>(out)[row] = o;
        }
    }
}

extern "C" void kernel_launch(void* const* d_in, const int* in_sizes, int n_in,
                              void* d_out, int out_size, void* d_ws, size_t ws_size,
                              hipStream_t stream) {
    const float* X = (const float*)d_in[0];
    const float* A = (const float*)d_in[1];
    float* out = (float*)d_out;
    const int B = in_sizes[0] / 64;

    hipLaunchKernelGGL(prep, dim3(1), dim3(64), 0, stream, A, d_ws);
    hipLaunchKernelGGL(decode, dim3(512), dim3(128), 0, stream,
                       X, out, (const float*)d_ws, B);
    hipLaunchKernelGGL(repair, dim3(128), dim3(256), 0, stream, X, out, d_ws, B);
}